// Round 1
// baseline (91.189 us; speedup 1.0000x reference)
//
#include <hip/hip_runtime.h>

// Problem constants (fixed by reference)
#define BS      16
#define CIN     32
#define COUT    64
#define OUT_DIM 1024
#define PK      4              // patch size K
#define DD      4096           // input spatial length

// out[b,o,p] = (1/sqrt(32)) * sum_{c,k} x[b,c,4p+k] * w[o,c,4p+k]
//
// Block: 4 consecutive patches (d-range of 16 floats = 64B, aligned) x 32 o x 16 b.
// Grid: 512 = 256 patch-groups x 2 o-halves. gg and gg+256 share bid%8 -> same XCD,
// so the x tile is HBM-fetched once per patch group (second reader hits L2).
// Thread (256/block): p_local = t&3, o_idx = (t>>2)&15 (2 consecutive o's),
// b_group = t>>6 (4 b's). 8 accumulators/thread.
__global__ __launch_bounds__(256, 2) void nolc1d_kernel(
    const float* __restrict__ x,
    const float* __restrict__ w,
    float* __restrict__ out)
{
    const int t   = threadIdx.x;
    const int bid = blockIdx.x;
    const int gg  = bid & 255;   // patch group: patches 4*gg .. 4*gg+3
    const int oh  = bid >> 8;    // o half: 0 or 1

    // x tile: [b][c][16 d-floats] = 16*32*16 floats = 32 KB
    __shared__ float xs[BS * CIN * 16];
    float4* xs4 = (float4*)xs;

    const float4* __restrict__ x4p = (const float4*)x;
    // Stage x: 2048 float4 slots, 8 per thread. 4 consecutive lanes load one
    // contiguous 64B segment per (b,c) row.
    #pragma unroll
    for (int l = 0; l < 8; ++l) {
        int idx  = t + l * 256;       // float4 slot 0..2047
        int pair = idx >> 2;          // (b,c): b = pair>>5, c = pair&31
        int i    = idx & 3;           // which float4 within the 64B segment
        int b    = pair >> 5;
        int c    = pair & 31;
        xs4[idx] = x4p[(size_t)b * (CIN * DD / 4) + c * (DD / 4) + gg * 4 + i];
    }
    __syncthreads();

    const int p_local = t & 3;
    const int o_idx   = (t >> 2) & 15;
    const int b0      = (t >> 6) * 4;
    const int o0      = oh * 32 + o_idx * 2;

    const float4* __restrict__ w4p = (const float4*)w;
    const size_t wstride_o = CIN * DD / 4;               // float4 units per o
    size_t wbase0 = (size_t)o0 * wstride_o + gg * 4 + p_local;
    size_t wbase1 = wbase0 + wstride_o;

    float acc[4][2] = {};

    #pragma unroll 8
    for (int c = 0; c < CIN; ++c) {
        // w loads: lanes (p 0..3) cover one 64B segment per o; coalesced.
        float4 wv0 = w4p[wbase0 + (size_t)c * (DD / 4)];
        float4 wv1 = w4p[wbase1 + (size_t)c * (DD / 4)];
        #pragma unroll
        for (int bi = 0; bi < 4; ++bi) {
            // broadcast across the 16 o-lanes sharing (b,c,p)
            float4 xv = xs4[((b0 + bi) * CIN + c) * 4 + p_local];
            acc[bi][0] += xv.x * wv0.x + xv.y * wv0.y + xv.z * wv0.z + xv.w * wv0.w;
            acc[bi][1] += xv.x * wv1.x + xv.y * wv1.y + xv.z * wv1.z + xv.w * wv1.w;
        }
    }

    const float scale = 0.17677669529663687f;  // 1/sqrt(32)
    const int pg = gg * 4 + p_local;
    #pragma unroll
    for (int bi = 0; bi < 4; ++bi) {
        #pragma unroll
        for (int j = 0; j < 2; ++j) {
            out[(size_t)(b0 + bi) * (COUT * OUT_DIM) +
                (size_t)(o0 + j) * OUT_DIM + pg] = acc[bi][j] * scale;
        }
    }
}

extern "C" void kernel_launch(void* const* d_in, const int* in_sizes, int n_in,
                              void* d_out, int out_size, void* d_ws, size_t ws_size,
                              hipStream_t stream) {
    const float* x = (const float*)d_in[0];   // [16][32][4096] fp32
    const float* w = (const float*)d_in[1];   // [64][32][4096] fp32
    float* out = (float*)d_out;               // [16][64][1024] fp32

    nolc1d_kernel<<<dim3(512), dim3(256), 0, stream>>>(x, w, out);
}